// Round 8
// baseline (922.177 us; speedup 1.0000x reference)
//
#include <hip/hip_runtime.h>
#include <math.h>

// Problem constants
#define BATCH 32
#define SEQ   512
#define DIN   512
#define IFACE 919
#define TAILC 274     // iface columns 645..918 are the only ones used
#define TAIL0 645

// ws float offsets
#define XM_PART 0        // 512 chunks * 512 floats = 262144 (partial seq sums)
#define EVO     262144   // 32*128 sigmoid(erase)
#define WVO     266240   // 32*128 write vector
#define WWH     270336   // 32*64  ww for n<64
#define SCAL    272384   // 32*2   [u, wwc]
// int-flag offsets (index into (unsigned int*)ws)
#define CFLAG   272448   // 512 chunk flags
#define WFLAG   272960   // 32*24 writer flags
#define MAGIC   0x13579BDFu

// d_out float offsets (tuple concat: out, memory, link, usage, prec, ww, rw)
#define OUT_OFF   0
#define MEM_OFF   16384
#define LINK_OFF  4210688      // 32*1024*1024 floats of exact zeros
#define USAGE_OFF 37765120
#define PREC_OFF  37797888
#define WW_OFF    37830656
#define RW_OFF    37863424

// link-zero work split: unit = 256 threads * 16 B = 4 KB
#define LINK_UNITS 32768
#define NRED  256        // reduce blocks (also first 32 = param blocks)
#define WR0   256        // writer blocks start
#define WPB   24         // writer blocks per batch (768 writers / 32 batches)
#define Q1    13         // link units per reduce block  [0, 3328)
#define Q1TOT 3328
#define Q2    39         // link units per writer block [3328, 32768), bound-checked

__device__ __forceinline__ float sigmoidf_(float x) { return 1.0f / (1.0f + expf(-x)); }

__global__ __launch_bounds__(256, 4) void k_all(const float* __restrict__ x,
                                                const float* __restrict__ Wif,
                                                float* __restrict__ ws,
                                                float* __restrict__ out) {
    const int bid = blockIdx.x, t = threadIdx.x;
    float4* link4 = (float4*)(out + LINK_OFF);
    unsigned int* wsi = (unsigned int*)ws;
    const float4 z4 = {0.f, 0.f, 0.f, 0.f};
    __shared__ float xms[DIN];
    __shared__ float p[TAILC];
    __shared__ float s_u, s_wwc, s_wwh[64];

    if (bid < NRED) {
        // ---- reduce: this block produces chunks 2*bid, 2*bid+1 ----
        int chunk = bid * 2 + (t >> 7), d4 = t & 127;
        int cb = chunk >> 4, cc = chunk & 15;
        const float4* xr = (const float4*)(x + (size_t)(cb * SEQ + cc * 32) * DIN);
        float4 acc = z4;
        for (int s = 0; s < 32; ++s) {
            float4 v = xr[s * 128 + d4];
            acc.x += v.x; acc.y += v.y; acc.z += v.z; acc.w += v.w;
        }
        ((float4*)(ws + XM_PART))[chunk * 128 + d4] = acc;
        __threadfence();
        __syncthreads();
        if (t == 0) {
            __hip_atomic_store(&wsi[CFLAG + bid * 2 + 0], MAGIC, __ATOMIC_RELEASE, __HIP_MEMORY_SCOPE_AGENT);
            __hip_atomic_store(&wsi[CFLAG + bid * 2 + 1], MAGIC, __ATOMIC_RELEASE, __HIP_MEMORY_SCOPE_AGENT);
        }
        // ---- link-zero quota ----
        int base = bid * Q1;
        #pragma unroll
        for (int i = 0; i < Q1; ++i) link4[(base + i) * 256 + t] = z4;

        if (bid >= 32) return;

        // ---- param path for batch bb = bid ----
        const int bb = bid;
        if (t == 0) {   // consume-and-clear the 16 chunk flags of this batch
            for (int i = 0; i < 16; ++i) {
                unsigned int* f = &wsi[CFLAG + bb * 16 + i];
                while (__hip_atomic_load(f, __ATOMIC_ACQUIRE, __HIP_MEMORY_SCOPE_AGENT) != MAGIC)
                    __builtin_amdgcn_s_sleep(2);
                __hip_atomic_store(f, 0u, __ATOMIC_RELAXED, __HIP_MEMORY_SCOPE_AGENT);
            }
        }
        __syncthreads();

        for (int d = t; d < DIN; d += 256) {   // finish two-stage reduce
            const float* q = ws + XM_PART + (size_t)bb * 16 * DIN + d;
            float s = 0.f;
            #pragma unroll
            for (int c = 0; c < 16; ++c) s += q[c * DIN];
            xms[d] = s;
        }
        __syncthreads();
        for (int j = t; j < TAILC; j += 256) { // GEMV: one column per thread
            const float* wcol = Wif + TAIL0 + j;
            float acc = 0.f;
            #pragma unroll 8
            for (int k = 0; k < DIN; ++k) acc += xms[k] * wcol[(size_t)k * IFACE];
            p[j] = acc * (1.0f / SEQ);
        }
        __syncthreads();

        float rm1[4];                          // read_modes softmax, middle mode
        #pragma unroll
        for (int r = 0; r < 4; ++r) {
            float i0 = p[262 + r], i1 = p[266 + r], i2 = p[270 + r];
            float mx = fmaxf(i0, fmaxf(i1, i2));
            float e0 = expf(i0 - mx), e1 = expf(i1 - mx), e2 = expf(i2 - mx);
            rm1[r] = e1 / (e0 + e1 + e2);
        }
        if (t < 128) {
            ws[EVO + bb * 128 + t] = sigmoidf_(p[t]);   // sigmoid(erase)
            ws[WVO + bb * 128 + t] = p[128 + t];        // write vector
            float4 o = {1e-6f * rm1[0], 1e-6f * rm1[1], 1e-6f * rm1[2], 1e-6f * rm1[3]};
            ((float4*)(out + OUT_OFF))[bb * 128 + t] = o;
        }
        if (t == 0) {
            const float inv1024 = 1.0f / 1024.0f;
            float ret = 1.f;
            #pragma unroll
            for (int r = 0; r < 4; ++r) {
                float fg = sigmoidf_(p[256 + r]);
                ret *= (1.f - fg * rm1[r] * inv1024);
            }
            float u = 1e-6f * ret;                      // usage (constant over n)
            float ag = sigmoidf_(p[260]);
            float wg = sigmoidf_(p[261]);
            float wwc = wg * (1.f - ag) * inv1024;      // ww for n>=64 (alloc underflowed)
            s_u = u; s_wwc = wwc;
            ws[SCAL + bb * 2 + 0] = u;
            ws[SCAL + bb * 2 + 1] = wwc;
            float cum = 1.f;                            // same f32 cumprod as reference
            for (int n = 0; n < 64; ++n) {
                float alloc = (1.f - u) * cum;
                float w = wg * (ag * alloc + (1.f - ag) * inv1024);
                s_wwh[n] = w;
                ws[WWH + bb * 64 + n] = w;
                cum *= u;
            }
        }
        __syncthreads();

        // small outputs for this batch
        float uu = s_u, wwc = s_wwc;
        float4 rv = {rm1[0] * (1.0f / 1024.0f), rm1[1] * (1.0f / 1024.0f),
                     rm1[2] * (1.0f / 1024.0f), rm1[3] * (1.0f / 1024.0f)};
        for (int n = t; n < 1024; n += 256) {
            float ww = (n < 64) ? s_wwh[n] : wwc;
            out[USAGE_OFF + bb * 1024 + n] = uu;
            out[PREC_OFF + bb * 1024 + n]  = ww;   // prec = ww (prec0 = 0)
            out[WW_OFF + bb * 1024 + n]    = ww;
            ((float4*)out)[RW_OFF / 4 + bb * 1024 + n] = rv;
        }
        __threadfence();
        __syncthreads();
        if (t < WPB)   // publish params to this batch's 24 writer blocks
            __hip_atomic_store(&wsi[WFLAG + bb * WPB + t], MAGIC, __ATOMIC_RELEASE, __HIP_MEMORY_SCOPE_AGENT);
    } else {
        // ---- writer block ----
        int w = bid - WR0;                     // 0..767
        int base = Q1TOT + w * Q2;
        #pragma unroll
        for (int i = 0; i < Q2; ++i) {
            int u2 = base + i;
            if (u2 < LINK_UNITS) link4[u2 * 256 + t] = z4;
        }
        int b = w / WPB, k = w % WPB;
        if (t == 0) {   // consume-and-clear own writer flag
            unsigned int* f = &wsi[WFLAG + b * WPB + k];
            while (__hip_atomic_load(f, __ATOMIC_ACQUIRE, __HIP_MEMORY_SCOPE_AGENT) != MAGIC)
                __builtin_amdgcn_s_sleep(2);
            __hip_atomic_store(f, 0u, __ATOMIC_RELAXED, __HIP_MEMORY_SCOPE_AGENT);
        }
        __syncthreads();

        float wwc = ws[SCAL + b * 2 + 1];
        float4 e = ((const float4*)(ws + EVO))[b * 32 + (t & 31)];
        float4 v = ((const float4*)(ws + WVO))[b * 32 + (t & 31)];
        for (int u = k; u < 128; u += WPB) {   // memory-fill units of this batch
            int n = u * 8 + (t >> 5);
            float ww = (n < 64) ? ws[WWH + b * 64 + n] : wwc;
            float4 m;
            m.x = 1e-6f * (1.f - ww * e.x) + ww * v.x;
            m.y = 1e-6f * (1.f - ww * e.y) + ww * v.y;
            m.z = 1e-6f * (1.f - ww * e.z) + ww * v.z;
            m.w = 1e-6f * (1.f - ww * e.w) + ww * v.w;
            ((float4*)(out + MEM_OFF))[(b * 128 + u) * 256 + t] = m;
        }
    }
}

extern "C" void kernel_launch(void* const* d_in, const int* in_sizes, int n_in,
                              void* d_out, int out_size, void* d_ws, size_t ws_size,
                              hipStream_t stream) {
    const float* x   = (const float*)d_in[0];
    const float* Wif = (const float*)d_in[1];
    float* out = (float*)d_out;
    float* ws  = (float*)d_ws;

    k_all<<<1024, 256, 0, stream>>>(x, Wif, ws, out);
}

// Round 9
// 65.221 us; speedup vs baseline: 14.1392x; 14.1392x over previous
//
#include <hip/hip_runtime.h>
#include <math.h>

// Problem constants
#define BATCH 32
#define SEQ   512
#define DIN   512
#define IFACE 919
#define TAILC 274     // iface columns 645..918 are the only ones used
#define TAIL0 645

// ws float offsets
#define XM_PART 0        // 32*16*512 = 262144 (partial seq sums, 16 chunks/batch)
#define EVO     262144   // 32*128 sigmoid(erase)
#define WVO     266240   // 32*128 write vector
#define WWH     270336   // 32*64  ww for n<64
#define SCAL    272384   // 32*2   [u, wwc]
#define RWV     272448   // 32*4   rw per head

// d_out float offsets (tuple concat: out, memory, link, usage, prec, ww, rw)
#define OUT_OFF   0
#define MEM_OFF   16384
#define LINK_OFF  4210688      // 32*1024*1024 floats of exact zeros
#define USAGE_OFF 37765120
#define PREC_OFF  37797888
#define WW_OFF    37830656
#define RW_OFF    37863424

// kW: 1024 threads/block, ONE 16B store per thread
#define ZB 8192                // link: 8388608 float4 / 1024
#define MB 1024                // memory: 1048576 float4 / 1024
#define SB 32                  // small: 32768 threads / 1024

typedef float f32x4 __attribute__((ext_vector_type(4)));

__device__ __forceinline__ float sigmoidf_(float x) { return 1.0f / (1.0f + expf(-x)); }

// K1: partial reduce of x over seq. grid (16 chunks, 32 batch), 128 threads (float4/lane)
__global__ void k_reduce_x(const float* __restrict__ x, float* __restrict__ ws) {
    int c = blockIdx.x, b = blockIdx.y, t = threadIdx.x;
    const float4* xr = (const float4*)(x + (size_t)(b * SEQ + c * 32) * DIN);
    float4 acc = {0.f, 0.f, 0.f, 0.f};
    for (int s = 0; s < 32; ++s) {
        float4 v = xr[s * 128 + t];
        acc.x += v.x; acc.y += v.y; acc.z += v.z; acc.w += v.w;
    }
    ((float4*)(ws + XM_PART))[(b * 16 + c) * 128 + t] = acc;
}

// K2: one block per batch, 512 threads. Finish reduce -> GEMV (1 col/thread) -> params.
__global__ __launch_bounds__(512) void kB(float* __restrict__ ws,
                                          const float* __restrict__ Wif,
                                          float* __restrict__ out) {
    __shared__ float xms[DIN];
    __shared__ float p[TAILC];
    int b = blockIdx.x, t = threadIdx.x;

    {   // finish the two-stage reduce: sum 16 partials for dim t
        const float* q = ws + XM_PART + (size_t)b * 16 * DIN + t;
        float s = 0.f;
        #pragma unroll
        for (int c = 0; c < 16; ++c) s += q[c * DIN];
        xms[t] = s;
    }
    __syncthreads();

    if (t < TAILC) {   // GEMV: one column per thread (coalesced over t per k)
        const float* wcol = Wif + TAIL0 + t;
        float acc = 0.f;
        #pragma unroll 8
        for (int k = 0; k < DIN; ++k) acc += xms[k] * wcol[(size_t)k * IFACE];
        p[t] = acc * (1.0f / SEQ);
    }
    __syncthreads();

    // read_modes softmax, middle mode (redundant per thread, reads shared p)
    float rm1[4];
    #pragma unroll
    for (int r = 0; r < 4; ++r) {
        float i0 = p[262 + r], i1 = p[266 + r], i2 = p[270 + r];
        float mx = fmaxf(i0, fmaxf(i1, i2));
        float e0 = expf(i0 - mx), e1 = expf(i1 - mx), e2 = expf(i2 - mx);
        rm1[r] = e1 / (e0 + e1 + e2);
    }

    if (t < 128) {
        ws[EVO + b * 128 + t] = sigmoidf_(p[t]);          // sigmoid(erase)
        ws[WVO + b * 128 + t] = p[128 + t];               // write vector
        // out[b, w*4+r] = 1e-6 * read_modes[1][r]  (read_vectors collapse)
        float4 o = {1e-6f * rm1[0], 1e-6f * rm1[1], 1e-6f * rm1[2], 1e-6f * rm1[3]};
        ((float4*)(out + OUT_OFF))[b * 128 + t] = o;
    }

    if (t == 0) {
        const float inv1024 = 1.0f / 1024.0f;
        float ret = 1.f;
        #pragma unroll
        for (int r = 0; r < 4; ++r) {
            ws[RWV + b * 4 + r] = rm1[r] * inv1024;       // rw value per head
            float fg = sigmoidf_(p[256 + r]);
            ret *= (1.f - fg * rm1[r] * inv1024);
        }
        float u = 1e-6f * ret;                            // usage (constant over n)
        float ag = sigmoidf_(p[260]);
        float wg = sigmoidf_(p[261]);
        ws[SCAL + b * 2 + 0] = u;
        ws[SCAL + b * 2 + 1] = wg * (1.f - ag) * inv1024; // ww for n>=64 (alloc underflowed)
        float cum = 1.f;                                  // same f32 cumprod as reference
        for (int n = 0; n < 64; ++n) {
            float alloc = (1.f - u) * cum;
            ws[WWH + b * 64 + n] = wg * (ag * alloc + (1.f - ag) * inv1024);
            cum *= u;
        }
    }
}

// K3 (kW): all output writes, ONE 16B NT store per thread, 1024-thread blocks.
// blocks [0,ZB): link zeros; [ZB, ZB+MB): memory fill; [ZB+MB, ZB+MB+SB): small.
__global__ __launch_bounds__(1024) void kW(const float* __restrict__ ws,
                                           float* __restrict__ out) {
    int bid = blockIdx.x, t = threadIdx.x;
    if (bid < ZB) {
        int idx = bid * 1024 + t;               // < 8388608 float4
        f32x4 z = {0.f, 0.f, 0.f, 0.f};
        __builtin_nontemporal_store(z, &((f32x4*)(out + LINK_OFF))[idx]);
    } else if (bid < ZB + MB) {
        int idx = (bid - ZB) * 1024 + t;        // < 1048576 float4
        int w4 = idx & 31;
        int n  = (idx >> 5) & 1023;
        int b  = idx >> 15;
        float ww = (n < 64) ? ws[WWH + b * 64 + n] : ws[SCAL + b * 2 + 1];
        float4 e = ((const float4*)(ws + EVO))[b * 32 + w4];
        float4 v = ((const float4*)(ws + WVO))[b * 32 + w4];
        f32x4 m;
        m.x = 1e-6f * (1.f - ww * e.x) + ww * v.x;
        m.y = 1e-6f * (1.f - ww * e.y) + ww * v.y;
        m.z = 1e-6f * (1.f - ww * e.z) + ww * v.z;
        m.w = 1e-6f * (1.f - ww * e.w) + ww * v.w;
        __builtin_nontemporal_store(m, &((f32x4*)(out + MEM_OFF))[idx]);
    } else {
        int t2 = (bid - ZB - MB) * 1024 + t;    // < 32768
        int b = t2 >> 10, n = t2 & 1023;
        float u  = ws[SCAL + b * 2 + 0];
        float ww = (n < 64) ? ws[WWH + b * 64 + n] : ws[SCAL + b * 2 + 1];
        out[USAGE_OFF + t2] = u;
        out[PREC_OFF + t2]  = ww;   // prec = ww (prec0 = 0)
        out[WW_OFF + t2]    = ww;
        float4 rv = ((const float4*)(ws + RWV))[b];
        ((float4*)out)[RW_OFF / 4 + t2] = rv;   // rw[b,n,:] constant over n
    }
}

extern "C" void kernel_launch(void* const* d_in, const int* in_sizes, int n_in,
                              void* d_out, int out_size, void* d_ws, size_t ws_size,
                              hipStream_t stream) {
    const float* x   = (const float*)d_in[0];
    const float* Wif = (const float*)d_in[1];
    float* out = (float*)d_out;
    float* ws  = (float*)d_ws;

    k_reduce_x<<<dim3(16, 32), 128, 0, stream>>>(x, ws);
    kB<<<32, 512, 0, stream>>>(ws, Wif, out);
    kW<<<ZB + MB + SB, 1024, 0, stream>>>(ws, out);
}

// Round 10
// 59.906 us; speedup vs baseline: 15.3939x; 1.0887x over previous
//
#include <hip/hip_runtime.h>
#include <math.h>

// Problem constants
#define BATCH 32
#define SEQ   512
#define DIN   512
#define IFACE 919
#define TAILC 274     // iface columns 645..918 are the only ones used
#define TAIL0 645

// ws float offsets
#define XM_PART 0        // 32*16*512 = 262144 (partial seq sums, 16 chunks/batch)
#define EVO     262144   // 32*128 sigmoid(erase)
#define WVO     266240   // 32*128 write vector
#define WWH     270336   // 32*64  ww for n<64
#define SCAL    272384   // 32*2   [u, wwc]
#define RWV     272448   // 32*4   rw per head

// d_out float offsets (tuple concat: out, memory, link, usage, prec, ww, rw)
#define OUT_OFF   0
#define MEM_OFF   16384
#define LINK_OFF  4210688      // 32*1024*1024 floats of exact zeros
#define USAGE_OFF 37765120
#define PREC_OFF  37797888
#define WW_OFF    37830656
#define RW_OFF    37863424

// kW unit space (float4 units). Total = 9469952 = 9248 blocks * 1024 exactly.
#define L_END 8388608                  // link zeros
#define M_END (L_END + 1048576)        // memory fill
#define U_END (M_END + 8192)           // usage
#define P_END (U_END + 8192)           // prec
#define WW_END (P_END + 8192)          // ww
#define R_END (WW_END + 32768)         // rw
#define KW_BLOCKS 9248

__device__ __forceinline__ float sigmoidf_(float x) { return 1.0f / (1.0f + expf(-x)); }

// K1: partial reduce of x over seq. grid (16 chunks, 32 batch), 128 threads (float4/lane)
__global__ void k_reduce_x(const float* __restrict__ x, float* __restrict__ ws) {
    int c = blockIdx.x, b = blockIdx.y, t = threadIdx.x;
    const float4* xr = (const float4*)(x + (size_t)(b * SEQ + c * 32) * DIN);
    float4 acc = {0.f, 0.f, 0.f, 0.f};
    for (int s = 0; s < 32; ++s) {
        float4 v = xr[s * 128 + t];
        acc.x += v.x; acc.y += v.y; acc.z += v.z; acc.w += v.w;
    }
    ((float4*)(ws + XM_PART))[(b * 16 + c) * 128 + t] = acc;
}

// K2: one block per batch, 512 threads. Finish reduce -> GEMV (1 col/thread) -> params.
__global__ __launch_bounds__(512) void kB(float* __restrict__ ws,
                                          const float* __restrict__ Wif,
                                          float* __restrict__ out) {
    __shared__ float xms[DIN];
    __shared__ float p[TAILC];
    int b = blockIdx.x, t = threadIdx.x;

    {   // finish the two-stage reduce: sum 16 partials for dim t
        const float* q = ws + XM_PART + (size_t)b * 16 * DIN + t;
        float s = 0.f;
        #pragma unroll
        for (int c = 0; c < 16; ++c) s += q[c * DIN];
        xms[t] = s;
    }
    __syncthreads();

    if (t < TAILC) {   // GEMV: one column per thread (coalesced over t per k)
        const float* wcol = Wif + TAIL0 + t;
        float acc = 0.f;
        #pragma unroll 8
        for (int k = 0; k < DIN; ++k) acc += xms[k] * wcol[(size_t)k * IFACE];
        p[t] = acc * (1.0f / SEQ);
    }
    __syncthreads();

    // read_modes softmax, middle mode (redundant per thread, reads shared p)
    float rm1[4];
    #pragma unroll
    for (int r = 0; r < 4; ++r) {
        float i0 = p[262 + r], i1 = p[266 + r], i2 = p[270 + r];
        float mx = fmaxf(i0, fmaxf(i1, i2));
        float e0 = expf(i0 - mx), e1 = expf(i1 - mx), e2 = expf(i2 - mx);
        rm1[r] = e1 / (e0 + e1 + e2);
    }

    if (t < 128) {
        ws[EVO + b * 128 + t] = sigmoidf_(p[t]);          // sigmoid(erase)
        ws[WVO + b * 128 + t] = p[128 + t];               // write vector
        // out[b, w*4+r] = 1e-6 * read_modes[1][r]  (read_vectors collapse)
        float4 o = {1e-6f * rm1[0], 1e-6f * rm1[1], 1e-6f * rm1[2], 1e-6f * rm1[3]};
        ((float4*)(out + OUT_OFF))[b * 128 + t] = o;
    }

    if (t == 0) {
        const float inv1024 = 1.0f / 1024.0f;
        float ret = 1.f;
        #pragma unroll
        for (int r = 0; r < 4; ++r) {
            ws[RWV + b * 4 + r] = rm1[r] * inv1024;       // rw value per head
            float fg = sigmoidf_(p[256 + r]);
            ret *= (1.f - fg * rm1[r] * inv1024);
        }
        float u = 1e-6f * ret;                            // usage (constant over n)
        float ag = sigmoidf_(p[260]);
        float wg = sigmoidf_(p[261]);
        ws[SCAL + b * 2 + 0] = u;
        ws[SCAL + b * 2 + 1] = wg * (1.f - ag) * inv1024; // ww for n>=64 (alloc underflowed)
        float cum = 1.f;                                  // same f32 cumprod as reference
        for (int n = 0; n < 64; ++n) {
            float alloc = (1.f - u) * cum;
            ws[WWH + b * 64 + n] = wg * (ag * alloc + (1.f - ag) * inv1024);
            cum *= u;
        }
    }
}

// K3 (kW): all output writes. 9248 blocks x 256 threads x 4 plain float4 stores.
// Each block owns one contiguous 16 KB region (1024 float4 units).
__global__ __launch_bounds__(256) void kW(const float* __restrict__ ws,
                                          float* __restrict__ out) {
    const int t = threadIdx.x;
    float4* out4 = (float4*)out;
    const float4 z4 = {0.f, 0.f, 0.f, 0.f};
    #pragma unroll
    for (int i = 0; i < 4; ++i) {
        int idx = blockIdx.x * 1024 + i * 256 + t;
        if (idx < L_END) {
            out4[LINK_OFF / 4 + idx] = z4;
        } else if (idx < M_END) {
            int j = idx - L_END;
            int w4 = j & 31;
            int n  = (j >> 5) & 1023;
            int b  = j >> 15;
            float ww = (n < 64) ? ws[WWH + b * 64 + n] : ws[SCAL + b * 2 + 1];
            float4 e = ((const float4*)(ws + EVO))[b * 32 + w4];
            float4 v = ((const float4*)(ws + WVO))[b * 32 + w4];
            float4 m;
            m.x = 1e-6f * (1.f - ww * e.x) + ww * v.x;
            m.y = 1e-6f * (1.f - ww * e.y) + ww * v.y;
            m.z = 1e-6f * (1.f - ww * e.z) + ww * v.z;
            m.w = 1e-6f * (1.f - ww * e.w) + ww * v.w;
            out4[MEM_OFF / 4 + j] = m;
        } else if (idx < U_END) {
            int j = idx - M_END;               // 0..8191; b = j>>8
            float u = ws[SCAL + (j >> 8) * 2 + 0];
            float4 uv = {u, u, u, u};
            out4[USAGE_OFF / 4 + j] = uv;
        } else if (idx < WW_END) {
            int j = (idx < P_END) ? idx - U_END : idx - P_END;
            int b = j >> 8, n0 = (j & 255) * 4;
            float wwc = ws[SCAL + b * 2 + 1];
            float4 wv;
            wv.x = (n0 + 0 < 64) ? ws[WWH + b * 64 + n0 + 0] : wwc;
            wv.y = (n0 + 1 < 64) ? ws[WWH + b * 64 + n0 + 1] : wwc;
            wv.z = (n0 + 2 < 64) ? ws[WWH + b * 64 + n0 + 2] : wwc;
            wv.w = (n0 + 3 < 64) ? ws[WWH + b * 64 + n0 + 3] : wwc;
            // prec = ww (prec0 = 0)
            out4[((idx < P_END) ? PREC_OFF : WW_OFF) / 4 + j] = wv;
        } else {
            int j = idx - WW_END;              // 0..32767; b = j>>10
            float4 rv = ((const float4*)(ws + RWV))[j >> 10];
            out4[RW_OFF / 4 + j] = rv;         // rw[b,n,:] constant over n
        }
    }
}

extern "C" void kernel_launch(void* const* d_in, const int* in_sizes, int n_in,
                              void* d_out, int out_size, void* d_ws, size_t ws_size,
                              hipStream_t stream) {
    const float* x   = (const float*)d_in[0];
    const float* Wif = (const float*)d_in[1];
    float* out = (float*)d_out;
    float* ws  = (float*)d_ws;

    k_reduce_x<<<dim3(16, 32), 128, 0, stream>>>(x, ws);
    kB<<<32, 512, 0, stream>>>(ws, Wif, out);
    kW<<<KW_BLOCKS, 256, 0, stream>>>(ws, out);
}